// Round 7
// baseline (478.581 us; speedup 1.0000x reference)
//
#include <hip/hip_runtime.h>
#include <math.h>
#include <float.h>

#define BATCH 8
#define HIGH  256
#define LOWR  64
#define NN    4096          // LOWR*LOWR
#define HIDC  16
#define C1    64
#define NSL   16            // j-slices in kNN scan (256 j each)

// workspace layout (floats) — footprint identical to the validated R1/R2 layout
#define OFF_XL   0
#define OFF_H1   (OFF_XL  + BATCH*NN)            // 2,097,152 floats; reused for cand_i
#define OFF_H    (OFF_H1  + BATCH*C1*NN)         // node-major [B*N][16]
#define OFF_SQ   (OFF_H   + BATCH*NN*HIDC)       // 0.5*|h|^2 per node
#define OFF_XP   (OFF_SQ  + BATCH*NN)
#define OFF_ASR  (OFF_XP  + BATCH*NN*HIDC)
#define OFF_ADT  (OFF_ASR + BATCH*NN*4)
#define OFF_P    (OFF_ADT + BATCH*NN*4)
#define OFF_OL   (OFF_P   + BATCH*NN*HIDC)
// cand_i: BATCH*NSL*NN uint4 = 8*16*4096*16 B = 8 MB = 2,097,152 float-slots
//         == exactly the h1 region (BATCH*C1*NN floats). No footprint growth.

// identical-arithmetic dot used by BOTH k_scan and k_merge (bit-equal scores)
__device__ __forceinline__ float dot16m(const float ni[16], float4 a0, float4 a1,
                                        float4 a2, float4 a3, float hs) {
    return ni[0]*a0.x + ni[1]*a0.y + ni[2]*a0.z + ni[3]*a0.w
         + ni[4]*a1.x + ni[5]*a1.y + ni[6]*a1.z + ni[7]*a1.w
         + ni[8]*a2.x + ni[9]*a2.y + ni[10]*a2.z + ni[11]*a2.w
         + ni[12]*a3.x + ni[13]*a3.y + ni[14]*a3.z + ni[15]*a3.w
         - hs;
}

// float/int dual-array top-8 insert (strict > : earliest j kept on ties)
__device__ __forceinline__ void fins8(float s[8], int id[8], float sc, int j) {
    s[7] = sc; id[7] = j;
#pragma unroll
    for (int k = 7; k > 0; k--) {
        if (s[k] > s[k - 1]) {
            float td = s[k]; s[k] = s[k - 1]; s[k - 1] = td;
            int tj = id[k]; id[k] = id[k - 1]; id[k - 1] = tj;
        }
    }
}

// lex (score desc, idx asc) insert for the merge (matches jax top_k tie rule)
__device__ __forceinline__ void lins8(float s[8], int id[8], float sc, int j) {
    if ((sc > s[7]) || (sc == s[7] && j < id[7])) {
        s[7] = sc; id[7] = j;
#pragma unroll
        for (int k = 7; k > 0; k--) {
            if ((s[k] > s[k - 1]) || (s[k] == s[k - 1] && id[k] < id[k - 1])) {
                float td = s[k]; s[k] = s[k - 1]; s[k - 1] = td;
                int tj = id[k]; id[k] = id[k - 1]; id[k - 1] = tj;
            }
        }
    }
}

// ---------------- bilinear downsample 256 -> 64 (antialiased triangle) -------
__global__ void k_down(const float* __restrict__ x, float* __restrict__ xl) {
    int t = blockIdx.x * 128 + threadIdx.x;
    if (t >= BATCH * NN) return;
    int b = t >> 12, oy = (t >> 6) & 63, ox = t & 63;
    const float* xb = x + b * HIGH * HIGH;
    float cy = 4.f * oy + 1.5f, cx = 4.f * ox + 1.5f;
    float wy[8], wx[8], sy = 0.f, sx = 0.f;
#pragma unroll
    for (int k = 0; k < 8; k++) {
        int iy = 4 * oy - 2 + k;
        float w = 1.f - fabsf((float)iy - cy) * 0.25f;
        if (iy < 0 || iy >= HIGH) w = 0.f;
        wy[k] = w; sy += w;
        int ix = 4 * ox - 2 + k;
        float v = 1.f - fabsf((float)ix - cx) * 0.25f;
        if (ix < 0 || ix >= HIGH) v = 0.f;
        wx[k] = v; sx += v;
    }
    float acc = 0.f;
#pragma unroll
    for (int ky = 0; ky < 8; ky++) {
        if (wy[ky] == 0.f) continue;
        int iy = 4 * oy - 2 + ky;
        float rowacc = 0.f;
#pragma unroll
        for (int kx = 0; kx < 8; kx++) {
            if (wx[kx] == 0.f) continue;
            int ix = 4 * ox - 2 + kx;
            rowacc += wx[kx] * xb[iy * HIGH + ix];
        }
        acc += wy[ky] * rowacc;
    }
    xl[t] = acc / (sy * sx);
}

// ---------------- conv3x3 1->64 + BN + relu ---------------------------------
__global__ void k_conv1(const float* __restrict__ xl, const float* __restrict__ W1,
                        const float* __restrict__ b1, const float* __restrict__ g1,
                        const float* __restrict__ be1, const float* __restrict__ m1,
                        const float* __restrict__ v1, float* __restrict__ h1) {
    int t = blockIdx.x * 256 + threadIdx.x;
    if (t >= BATCH * C1 * NN) return;
    int b = t >> 18, co = (t >> 12) & 63, y = (t >> 6) & 63, x = t & 63;
    const float* src = xl + b * NN;
    const float* w = W1 + co * 9;
    float acc = 0.f;
#pragma unroll
    for (int dy = -1; dy <= 1; dy++) {
        int yy = y + dy; if (yy < 0 || yy >= 64) continue;
#pragma unroll
        for (int dx = -1; dx <= 1; dx++) {
            int xx = x + dx; if (xx < 0 || xx >= 64) continue;
            acc += w[(dy + 1) * 3 + (dx + 1)] * src[yy * 64 + xx];
        }
    }
    acc += b1[co];
    float sc = g1[co] / sqrtf(v1[co] + 1e-5f);
    acc = (acc - m1[co]) * sc + be1[co];
    h1[t] = fmaxf(acc, 0.f);
}

// ------- conv3x3 64->16 + BN + relu, split over 2 output-channel halves ------
__launch_bounds__(128)
__global__ void k_conv2o(const float* __restrict__ h1, const float* __restrict__ W2,
                         const float* __restrict__ b2, const float* __restrict__ g2,
                         const float* __restrict__ be2, const float* __restrict__ m2,
                         const float* __restrict__ v2, float* __restrict__ h) {
    __shared__ float sW[576 * 8];       // [ci*9+tap][o']
    int tid = threadIdx.x;
    int blk = blockIdx.x;
    int b = blk >> 6, ytile = (blk >> 1) & 31, oh = blk & 1;
    for (int k = tid; k < 4608; k += 128) {
        int o = k / 576, ct = k - o * 576;
        sW[ct * 8 + o] = W2[(oh * 8 + o) * 576 + ct];
    }
    __syncthreads();
    int ty = tid >> 6, x = tid & 63, y = ytile * 2 + ty;
    float acc[8];
#pragma unroll
    for (int o = 0; o < 8; o++) acc[o] = 0.f;
    const float* hb = h1 + (long)b * C1 * NN;
    for (int ci = 0; ci < 64; ci++) {
        const float* plane = hb + ci * NN;
#pragma unroll
        for (int dy = -1; dy <= 1; dy++) {
            int yy = y + dy; bool oky = (yy >= 0 && yy < 64);
#pragma unroll
            for (int dx = -1; dx <= 1; dx++) {
                int xx = x + dx;
                float v = (oky && xx >= 0 && xx < 64) ? plane[yy * 64 + xx] : 0.f;
                int ct = ci * 9 + (dy + 1) * 3 + (dx + 1);
                const float4* wr = (const float4*)&sW[ct * 8];
                float4 w0 = wr[0], w1 = wr[1];
                acc[0] += v * w0.x; acc[1] += v * w0.y; acc[2] += v * w0.z; acc[3] += v * w0.w;
                acc[4] += v * w1.x; acc[5] += v * w1.y; acc[6] += v * w1.z; acc[7] += v * w1.w;
            }
        }
    }
    int n = y * 64 + x;
    long node = (long)b * NN + n;
#pragma unroll
    for (int o2 = 0; o2 < 8; o2++) {
        int o = oh * 8 + o2;
        float a = acc[o2] + b2[o];
        float sc = g2[o] / sqrtf(v2[o] + 1e-5f);
        a = (a - m2[o]) * sc + be2[o];
        h[node * 16 + o] = fmaxf(a, 0.f);
    }
}

// ------- per-node derived features: sq (0.5|h|^2), xp = Wg h, asr, adt ------
__launch_bounds__(128)
__global__ void k_feats(const float* __restrict__ h, const float* __restrict__ Wg,
                        const float* __restrict__ a_src, const float* __restrict__ a_dst,
                        float* __restrict__ sq, float* __restrict__ xp,
                        float* __restrict__ asr, float* __restrict__ adt) {
    __shared__ float sWg[256];
    __shared__ float sA[32];
    int tid = threadIdx.x;
    for (int k = tid; k < 256; k += 128) sWg[k] = Wg[k];
    if (tid < 16) { sA[tid] = a_src[tid]; sA[16 + tid] = a_dst[tid]; }
    __syncthreads();
    long node = (long)blockIdx.x * 128 + tid;
    const float4* hp = (const float4*)&h[node * 16];
    float4 h0 = hp[0], h1v = hp[1], h2 = hp[2], h3 = hp[3];
    float nodev[16] = { h0.x,h0.y,h0.z,h0.w, h1v.x,h1v.y,h1v.z,h1v.w,
                        h2.x,h2.y,h2.z,h2.w, h3.x,h3.y,h3.z,h3.w };
    float sqv = 0.f;
#pragma unroll
    for (int o = 0; o < 16; o++) sqv += nodev[o] * nodev[o];
    sq[node] = 0.5f * sqv;
    float xpv[16];
#pragma unroll
    for (int o = 0; o < 16; o++) {
        float a = 0.f;
#pragma unroll
        for (int c = 0; c < 16; c++) a += sWg[o * 16 + c] * nodev[c];
        xpv[o] = a;
        xp[node * 16 + o] = a;
    }
#pragma unroll
    for (int hh = 0; hh < 4; hh++) {
        float as = 0.f, ad = 0.f;
#pragma unroll
        for (int f = 0; f < 4; f++) {
            as += xpv[hh * 4 + f] * sA[hh * 4 + f];
            ad += xpv[hh * 4 + f] * sA[16 + hh * 4 + f];
        }
        asr[node * 4 + hh] = as;
        adt[node * 4 + hh] = ad;
    }
}

// --------- kNN scan: 2 rows/thread, per (rows, 256-j slice) top-8 -----------
// block = 256 threads owning rows i0 = rg*512+tid, i1 = i0+256; all threads
// scan the SAME 256-j slice in lock-step (wave-uniform j loads, no LDS).
// grid = 8 b * 8 rowgroups * 16 slices = 1024 blocks (4 waves/SIMD).
__launch_bounds__(256)
__global__ void k_scan(const float* __restrict__ h, const float* __restrict__ sq,
                       uint4* __restrict__ cand_i) {
    int tid = threadIdx.x;
    int blk = blockIdx.x;
    int b  = blk >> 7;
    int rg = (blk >> 4) & 7;
    int sl = blk & 15;
    int i0 = rg * 512 + tid, i1 = i0 + 256;
    long bN = (long)b * NN;
    float ni0[16], ni1[16];
    {
        const float4* p0 = (const float4*)&h[(bN + i0) * 16];
        float4 r0 = p0[0], r1 = p0[1], r2 = p0[2], r3 = p0[3];
        ni0[0]=r0.x; ni0[1]=r0.y; ni0[2]=r0.z; ni0[3]=r0.w;
        ni0[4]=r1.x; ni0[5]=r1.y; ni0[6]=r1.z; ni0[7]=r1.w;
        ni0[8]=r2.x; ni0[9]=r2.y; ni0[10]=r2.z; ni0[11]=r2.w;
        ni0[12]=r3.x; ni0[13]=r3.y; ni0[14]=r3.z; ni0[15]=r3.w;
        const float4* p1 = (const float4*)&h[(bN + i1) * 16];
        float4 q0 = p1[0], q1 = p1[1], q2 = p1[2], q3 = p1[3];
        ni1[0]=q0.x; ni1[1]=q0.y; ni1[2]=q0.z; ni1[3]=q0.w;
        ni1[4]=q1.x; ni1[5]=q1.y; ni1[6]=q1.z; ni1[7]=q1.w;
        ni1[8]=q2.x; ni1[9]=q2.y; ni1[10]=q2.z; ni1[11]=q2.w;
        ni1[12]=q3.x; ni1[13]=q3.y; ni1[14]=q3.z; ni1[15]=q3.w;
    }
    float s0[8], s1[8]; int id0[8], id1[8];
#pragma unroll
    for (int k = 0; k < 8; k++) {
        s0[k] = -FLT_MAX; id0[k] = 65535;
        s1[k] = -FLT_MAX; id1[k] = 65535;
    }
    int j0 = sl * 256;
    const float* __restrict__ hj  = h + (bN + j0) * 16;
    const float* __restrict__ sqp = sq + bN + j0;
#pragma unroll 4
    for (int q = 0; q < 256; q++) {
        const float4* np = (const float4*)(hj + q * 16);
        float4 a0 = np[0], a1 = np[1], a2 = np[2], a3 = np[3];
        float hs = sqp[q];
        int j = j0 + q;
        float sc0 = dot16m(ni0, a0, a1, a2, a3, hs);
        float sc1 = dot16m(ni1, a0, a1, a2, a3, hs);
        if (sc0 > s0[7] && j != i0) fins8(s0, id0, sc0, j);
        if (sc1 > s1[7] && j != i1) fins8(s1, id1, sc1, j);
    }
    long base = (long)(b * NSL + sl) * NN;
    uint4 pk0, pk1;
    pk0.x = (unsigned)id0[0] | ((unsigned)id0[1] << 16);
    pk0.y = (unsigned)id0[2] | ((unsigned)id0[3] << 16);
    pk0.z = (unsigned)id0[4] | ((unsigned)id0[5] << 16);
    pk0.w = (unsigned)id0[6] | ((unsigned)id0[7] << 16);
    pk1.x = (unsigned)id1[0] | ((unsigned)id1[1] << 16);
    pk1.y = (unsigned)id1[2] | ((unsigned)id1[3] << 16);
    pk1.z = (unsigned)id1[4] | ((unsigned)id1[5] << 16);
    pk1.w = (unsigned)id1[6] | ((unsigned)id1[7] << 16);
    cand_i[base + i0] = pk0;
    cand_i[base + i1] = pk1;
}

// --- merge 16 slice-lists (4 slots x 4 slices, rescore bit-identically) -----
// + GAT epilogue -> p.  grid = 8 b * 64 rowgroups = 512 blocks.
__launch_bounds__(256)
__global__ void k_merge(const uint4* __restrict__ cand_i, const float* __restrict__ h,
                        const float* __restrict__ sq, const float* __restrict__ xp,
                        const float* __restrict__ asr, const float* __restrict__ adt,
                        const float* __restrict__ bg, float* __restrict__ p) {
    __shared__ float ms[64 * 3 * 8];
    __shared__ short mi[64 * 3 * 8];
    int tid = threadIdx.x;
    int blk = blockIdx.x;
    int b = blk >> 6, rg = blk & 63;
    int r = tid & 63, slot = tid >> 6;
    int i = rg * 64 + r;
    long bN = (long)b * NN;
    const float4* ip = (const float4*)&h[(bN + i) * 16];
    float4 q0 = ip[0], q1 = ip[1], q2 = ip[2], q3 = ip[3];
    float ni[16] = { q0.x,q0.y,q0.z,q0.w, q1.x,q1.y,q1.z,q1.w,
                     q2.x,q2.y,q2.z,q2.w, q3.x,q3.y,q3.z,q3.w };
    float fS[8]; int fI[8];
#pragma unroll
    for (int k = 0; k < 8; k++) { fS[k] = -FLT_MAX; fI[k] = 65535; }
#pragma unroll
    for (int s2 = 0; s2 < 4; s2++) {
        int sl = slot * 4 + s2;
        uint4 pk = cand_i[(long)(b * NSL + sl) * NN + i];
        unsigned idx8[8] = { pk.x & 0xFFFF, pk.x >> 16, pk.y & 0xFFFF, pk.y >> 16,
                             pk.z & 0xFFFF, pk.z >> 16, pk.w & 0xFFFF, pk.w >> 16 };
#pragma unroll
        for (int k = 0; k < 8; k++) {
            int j = (int)idx8[k];
            const float4* np = (const float4*)&h[(bN + j) * 16];
            float4 a0 = np[0], a1 = np[1], a2 = np[2], a3 = np[3];
            float sc = dot16m(ni, a0, a1, a2, a3, sq[bN + j]);  // bit-identical to scan
            lins8(fS, fI, sc, j);
        }
    }
    if (slot != 0) {
        float* ds = &ms[(r * 3 + slot - 1) * 8];
        short* di = &mi[(r * 3 + slot - 1) * 8];
#pragma unroll
        for (int k = 0; k < 8; k++) { ds[k] = fS[k]; di[k] = (short)fI[k]; }
    }
    __syncthreads();
    if (slot == 0) {
        for (int s = 0; s < 3; s++) {
            const float* ds = &ms[(r * 3 + s) * 8];
            const short* di = &mi[(r * 3 + s) * 8];
#pragma unroll
            for (int k = 0; k < 8; k++) lins8(fS, fI, ds[k], (int)di[k]);
        }
        int nbrs[9];
#pragma unroll
        for (int e = 0; e < 8; e++) nbrs[e] = fI[e];
        nbrs[8] = i;                                   // self-loop
        float adtv[4];
#pragma unroll
        for (int hh = 0; hh < 4; hh++) adtv[hh] = adt[(bN + i) * 4 + hh];
        float mx[4] = { -FLT_MAX, -FLT_MAX, -FLT_MAX, -FLT_MAX };
        float lg[9][4];
#pragma unroll
        for (int e = 0; e < 9; e++) {
            long nb = bN + nbrs[e];
#pragma unroll
            for (int hh = 0; hh < 4; hh++) {
                float l = asr[nb * 4 + hh] + adtv[hh];
                l = (l > 0.f) ? l : 0.2f * l;          // leaky_relu 0.2
                lg[e][hh] = l;
                mx[hh] = fmaxf(mx[hh], l);
            }
        }
        float sum[4] = { 0, 0, 0, 0 };
        float acc[16];
#pragma unroll
        for (int c = 0; c < 16; c++) acc[c] = 0.f;
#pragma unroll
        for (int e = 0; e < 9; e++) {
            long nb = bN + nbrs[e];
            const float4* xpn = (const float4*)&xp[nb * 16];
            float4 x0 = xpn[0], x1 = xpn[1], x2 = xpn[2], x3 = xpn[3];
            float xv[16] = { x0.x,x0.y,x0.z,x0.w, x1.x,x1.y,x1.z,x1.w,
                             x2.x,x2.y,x2.z,x2.w, x3.x,x3.y,x3.z,x3.w };
            float wv[4];
#pragma unroll
            for (int hh = 0; hh < 4; hh++) {
                float w = expf(lg[e][hh] - mx[hh]);
                sum[hh] += w; wv[hh] = w;
            }
#pragma unroll
            for (int hh = 0; hh < 4; hh++)
#pragma unroll
                for (int f = 0; f < 4; f++)
                    acc[hh * 4 + f] += wv[hh] * xv[hh * 4 + f];
        }
#pragma unroll
        for (int hh = 0; hh < 4; hh++) {
            float inv = 1.f / sum[hh];
#pragma unroll
            for (int f = 0; f < 4; f++) {
                float o = acc[hh * 4 + f] * inv + bg[hh * 4 + f];
                p[(bN + i) * 16 + hh * 4 + f] = fmaxf(o, 0.f);
            }
        }
    }
}

// ------- 1x1 MLP 16->128->16, fire mask, h += mask*u, 1x1->1 + sigmoid ------
// weights read with wave-uniform indices -> scalar loads, no LDS, no barrier.
__launch_bounds__(128)
__global__ void k_update(const float* __restrict__ p, const float* __restrict__ h,
                         const float* __restrict__ fire, const float* __restrict__ Wu1,
                         const float* __restrict__ bu1, const float* __restrict__ Wu2,
                         const float* __restrict__ bu2, const float* __restrict__ Wo,
                         const float* __restrict__ bo, float* __restrict__ out_low) {
    int tid = threadIdx.x;
    long n = (long)blockIdx.x * 128 + tid;           // 0..32767
    const float4* pp = (const float4*)&p[n * 16];
    float4 p0 = pp[0], p1 = pp[1], p2 = pp[2], p3 = pp[3];
    float pv[16] = { p0.x,p0.y,p0.z,p0.w, p1.x,p1.y,p1.z,p1.w,
                     p2.x,p2.y,p2.z,p2.w, p3.x,p3.y,p3.z,p3.w };
    float u[16];
#pragma unroll
    for (int c = 0; c < 16; c++) u[c] = bu2[c];
#pragma unroll 2
    for (int hd = 0; hd < 128; hd++) {
        float a = bu1[hd];
#pragma unroll
        for (int c = 0; c < 16; c++) a += Wu1[hd * 16 + c] * pv[c];   // scalar W
        a = fmaxf(a, 0.f);
#pragma unroll
        for (int c = 0; c < 16; c++) u[c] += Wu2[c * 128 + hd] * a;   // scalar W
    }
    float mask = (fire[n] < 0.5f) ? 1.f : 0.f;
    const float4* hp = (const float4*)&h[n * 16];
    float4 h0 = hp[0], h1v = hp[1], h2 = hp[2], h3 = hp[3];
    float hv[16] = { h0.x,h0.y,h0.z,h0.w, h1v.x,h1v.y,h1v.z,h1v.w,
                     h2.x,h2.y,h2.z,h2.w, h3.x,h3.y,h3.z,h3.w };
    float o = bo[0];
#pragma unroll
    for (int c = 0; c < 16; c++) o += Wo[c] * (hv[c] + mask * u[c]);
    out_low[n] = 1.f / (1.f + expf(-o));
}

// ---------------- bilinear upsample 64 -> 256 (half-pixel, clamp) -----------
__global__ void k_up(const float* __restrict__ ol, float* __restrict__ out) {
    int t = blockIdx.x * 256 + threadIdx.x;
    if (t >= BATCH * HIGH * HIGH) return;
    int b = t >> 16, oy = (t >> 8) & 255, ox = t & 255;
    float cy = (oy + 0.5f) * 0.25f - 0.5f;
    float cx = (ox + 0.5f) * 0.25f - 0.5f;
    int iy0 = (int)floorf(cy); float fy = cy - (float)iy0;
    int ix0 = (int)floorf(cx); float fx = cx - (float)ix0;
    int y0 = min(max(iy0, 0), 63), y1 = min(max(iy0 + 1, 0), 63);
    int x0 = min(max(ix0, 0), 63), x1 = min(max(ix0 + 1, 0), 63);
    const float* s = ol + b * NN;
    float v = (1.f - fy) * ((1.f - fx) * s[y0 * 64 + x0] + fx * s[y0 * 64 + x1])
            + fy * ((1.f - fx) * s[y1 * 64 + x0] + fx * s[y1 * 64 + x1]);
    out[t] = v;
}

extern "C" void kernel_launch(void* const* d_in, const int* in_sizes, int n_in,
                              void* d_out, int out_size, void* d_ws, size_t ws_size,
                              hipStream_t stream) {
    const float* x    = (const float*)d_in[0];
    const float* fire = (const float*)d_in[1];
    const float* W1   = (const float*)d_in[2];
    const float* b1   = (const float*)d_in[3];
    const float* g1   = (const float*)d_in[4];
    const float* be1  = (const float*)d_in[5];
    const float* m1   = (const float*)d_in[6];
    const float* v1   = (const float*)d_in[7];
    const float* W2   = (const float*)d_in[8];
    const float* b2   = (const float*)d_in[9];
    const float* g2   = (const float*)d_in[10];
    const float* be2  = (const float*)d_in[11];
    const float* m2   = (const float*)d_in[12];
    const float* v2   = (const float*)d_in[13];
    const float* Wg   = (const float*)d_in[14];
    const float* a_src= (const float*)d_in[15];
    const float* a_dst= (const float*)d_in[16];
    const float* bg   = (const float*)d_in[17];
    const float* Wu1  = (const float*)d_in[18];
    const float* bu1  = (const float*)d_in[19];
    const float* Wu2  = (const float*)d_in[20];
    const float* bu2  = (const float*)d_in[21];
    const float* Wo   = (const float*)d_in[22];
    const float* bo   = (const float*)d_in[23];

    float* ws  = (float*)d_ws;
    float* xl  = ws + OFF_XL;
    float* h1  = ws + OFF_H1;
    float* h   = ws + OFF_H;
    float* sq  = ws + OFF_SQ;
    float* xp  = ws + OFF_XP;
    float* asr = ws + OFF_ASR;
    float* adt = ws + OFF_ADT;
    float* p   = ws + OFF_P;
    float* ol  = ws + OFF_OL;
    uint4* cand_i = (uint4*)(ws + OFF_H1);          // reuse h1 (dead after conv2o), 8 MB

    k_down  <<<(BATCH * NN + 127) / 128, 128, 0, stream>>>(x, xl);
    k_conv1 <<<(BATCH * C1 * NN) / 256, 256, 0, stream>>>(xl, W1, b1, g1, be1, m1, v1, h1);
    k_conv2o<<<BATCH * 32 * 2, 128, 0, stream>>>(h1, W2, b2, g2, be2, m2, v2, h);
    k_feats <<<BATCH * NN / 128, 128, 0, stream>>>(h, Wg, a_src, a_dst, sq, xp, asr, adt);
    k_scan  <<<BATCH * 8 * NSL, 256, 0, stream>>>(h, sq, cand_i);
    k_merge <<<BATCH * 64, 256, 0, stream>>>(cand_i, h, sq, xp, asr, adt, bg, p);
    k_update<<<BATCH * NN / 128, 128, 0, stream>>>(p, h, fire, Wu1, bu1, Wu2, bu2, Wo, bo, ol);
    k_up    <<<(BATCH * HIGH * HIGH) / 256, 256, 0, stream>>>(ol, (float*)d_out);
}

// Round 8
// 444.298 us; speedup vs baseline: 1.0772x; 1.0772x over previous
//
#include <hip/hip_runtime.h>
#include <math.h>
#include <float.h>

#define BATCH 8
#define HIGH  256
#define LOWR  64
#define NN    4096          // LOWR*LOWR
#define HIDC  16
#define C1    64
#define NSL   8             // j-slices in kNN scan (512 j each)

// workspace layout (floats) — footprint identical to the validated R1/R2 layout
#define OFF_XL   0
#define OFF_H1   (OFF_XL  + BATCH*NN)            // 2,097,152 floats; reused for cand_i
#define OFF_H    (OFF_H1  + BATCH*C1*NN)         // node-major [B*N][16]
#define OFF_SQ   (OFF_H   + BATCH*NN*HIDC)       // 0.5*|h|^2 per node
#define OFF_XP   (OFF_SQ  + BATCH*NN)
#define OFF_ASR  (OFF_XP  + BATCH*NN*HIDC)
#define OFF_ADT  (OFF_ASR + BATCH*NN*4)
#define OFF_P    (OFF_ADT + BATCH*NN*4)
#define OFF_OL   (OFF_P   + BATCH*NN*HIDC)
// cand_i: BATCH*NSL*NN uint4 = 4 MB = 1,048,576 float-slots at OFF_H1 (validated in R5)

// identical-arithmetic dot used by BOTH k_scan and k_merge (bit-equal scores)
__device__ __forceinline__ float dot16m(const float ni[16], float4 a0, float4 a1,
                                        float4 a2, float4 a3, float hs) {
    return ni[0]*a0.x + ni[1]*a0.y + ni[2]*a0.z + ni[3]*a0.w
         + ni[4]*a1.x + ni[5]*a1.y + ni[6]*a1.z + ni[7]*a1.w
         + ni[8]*a2.x + ni[9]*a2.y + ni[10]*a2.z + ni[11]*a2.w
         + ni[12]*a3.x + ni[13]*a3.y + ni[14]*a3.z + ni[15]*a3.w
         - hs;
}

// lex (score desc, idx asc) insert for the merge (matches jax top_k tie rule)
__device__ __forceinline__ void lins8(float s[8], int id[8], float sc, int j) {
    if ((sc > s[7]) || (sc == s[7] && j < id[7])) {
        s[7] = sc; id[7] = j;
#pragma unroll
        for (int k = 7; k > 0; k--) {
            if ((s[k] > s[k - 1]) || (s[k] == s[k - 1] && id[k] < id[k - 1])) {
                float td = s[k]; s[k] = s[k - 1]; s[k - 1] = td;
                int tj = id[k]; id[k] = id[k - 1]; id[k - 1] = tj;
            }
        }
    }
}

// ---------------- bilinear downsample 256 -> 64 (antialiased triangle) -------
__global__ void k_down(const float* __restrict__ x, float* __restrict__ xl) {
    int t = blockIdx.x * 128 + threadIdx.x;
    if (t >= BATCH * NN) return;
    int b = t >> 12, oy = (t >> 6) & 63, ox = t & 63;
    const float* xb = x + b * HIGH * HIGH;
    float cy = 4.f * oy + 1.5f, cx = 4.f * ox + 1.5f;
    float wy[8], wx[8], sy = 0.f, sx = 0.f;
#pragma unroll
    for (int k = 0; k < 8; k++) {
        int iy = 4 * oy - 2 + k;
        float w = 1.f - fabsf((float)iy - cy) * 0.25f;
        if (iy < 0 || iy >= HIGH) w = 0.f;
        wy[k] = w; sy += w;
        int ix = 4 * ox - 2 + k;
        float v = 1.f - fabsf((float)ix - cx) * 0.25f;
        if (ix < 0 || ix >= HIGH) v = 0.f;
        wx[k] = v; sx += v;
    }
    float acc = 0.f;
#pragma unroll
    for (int ky = 0; ky < 8; ky++) {
        if (wy[ky] == 0.f) continue;
        int iy = 4 * oy - 2 + ky;
        float rowacc = 0.f;
#pragma unroll
        for (int kx = 0; kx < 8; kx++) {
            if (wx[kx] == 0.f) continue;
            int ix = 4 * ox - 2 + kx;
            rowacc += wx[kx] * xb[iy * HIGH + ix];
        }
        acc += wy[ky] * rowacc;
    }
    xl[t] = acc / (sy * sx);
}

// ---------------- conv3x3 1->64 + BN + relu ---------------------------------
__global__ void k_conv1(const float* __restrict__ xl, const float* __restrict__ W1,
                        const float* __restrict__ b1, const float* __restrict__ g1,
                        const float* __restrict__ be1, const float* __restrict__ m1,
                        const float* __restrict__ v1, float* __restrict__ h1) {
    int t = blockIdx.x * 256 + threadIdx.x;
    if (t >= BATCH * C1 * NN) return;
    int b = t >> 18, co = (t >> 12) & 63, y = (t >> 6) & 63, x = t & 63;
    const float* src = xl + b * NN;
    const float* w = W1 + co * 9;
    float acc = 0.f;
#pragma unroll
    for (int dy = -1; dy <= 1; dy++) {
        int yy = y + dy; if (yy < 0 || yy >= 64) continue;
#pragma unroll
        for (int dx = -1; dx <= 1; dx++) {
            int xx = x + dx; if (xx < 0 || xx >= 64) continue;
            acc += w[(dy + 1) * 3 + (dx + 1)] * src[yy * 64 + xx];
        }
    }
    acc += b1[co];
    float sc = g1[co] / sqrtf(v1[co] + 1e-5f);
    acc = (acc - m1[co]) * sc + be1[co];
    h1[t] = fmaxf(acc, 0.f);
}

// ------- conv3x3 64->16 + BN + relu, split over 2 output-channel halves ------
__launch_bounds__(128)
__global__ void k_conv2o(const float* __restrict__ h1, const float* __restrict__ W2,
                         const float* __restrict__ b2, const float* __restrict__ g2,
                         const float* __restrict__ be2, const float* __restrict__ m2,
                         const float* __restrict__ v2, float* __restrict__ h) {
    __shared__ float sW[576 * 8];       // [ci*9+tap][o']
    int tid = threadIdx.x;
    int blk = blockIdx.x;
    int b = blk >> 6, ytile = (blk >> 1) & 31, oh = blk & 1;
    for (int k = tid; k < 4608; k += 128) {
        int o = k / 576, ct = k - o * 576;
        sW[ct * 8 + o] = W2[(oh * 8 + o) * 576 + ct];
    }
    __syncthreads();
    int ty = tid >> 6, x = tid & 63, y = ytile * 2 + ty;
    float acc[8];
#pragma unroll
    for (int o = 0; o < 8; o++) acc[o] = 0.f;
    const float* hb = h1 + (long)b * C1 * NN;
    for (int ci = 0; ci < 64; ci++) {
        const float* plane = hb + ci * NN;
#pragma unroll
        for (int dy = -1; dy <= 1; dy++) {
            int yy = y + dy; bool oky = (yy >= 0 && yy < 64);
#pragma unroll
            for (int dx = -1; dx <= 1; dx++) {
                int xx = x + dx;
                float v = (oky && xx >= 0 && xx < 64) ? plane[yy * 64 + xx] : 0.f;
                int ct = ci * 9 + (dy + 1) * 3 + (dx + 1);
                const float4* wr = (const float4*)&sW[ct * 8];
                float4 w0 = wr[0], w1 = wr[1];
                acc[0] += v * w0.x; acc[1] += v * w0.y; acc[2] += v * w0.z; acc[3] += v * w0.w;
                acc[4] += v * w1.x; acc[5] += v * w1.y; acc[6] += v * w1.z; acc[7] += v * w1.w;
            }
        }
    }
    int n = y * 64 + x;
    long node = (long)b * NN + n;
#pragma unroll
    for (int o2 = 0; o2 < 8; o2++) {
        int o = oh * 8 + o2;
        float a = acc[o2] + b2[o];
        float sc = g2[o] / sqrtf(v2[o] + 1e-5f);
        a = (a - m2[o]) * sc + be2[o];
        h[node * 16 + o] = fmaxf(a, 0.f);
    }
}

// ------- per-node derived features: sq (0.5|h|^2), xp = Wg h, asr, adt ------
__launch_bounds__(128)
__global__ void k_feats(const float* __restrict__ h, const float* __restrict__ Wg,
                        const float* __restrict__ a_src, const float* __restrict__ a_dst,
                        float* __restrict__ sq, float* __restrict__ xp,
                        float* __restrict__ asr, float* __restrict__ adt) {
    __shared__ float sWg[256];
    __shared__ float sA[32];
    int tid = threadIdx.x;
    for (int k = tid; k < 256; k += 128) sWg[k] = Wg[k];
    if (tid < 16) { sA[tid] = a_src[tid]; sA[16 + tid] = a_dst[tid]; }
    __syncthreads();
    long node = (long)blockIdx.x * 128 + tid;
    const float4* hp = (const float4*)&h[node * 16];
    float4 h0 = hp[0], h1v = hp[1], h2 = hp[2], h3 = hp[3];
    float nodev[16] = { h0.x,h0.y,h0.z,h0.w, h1v.x,h1v.y,h1v.z,h1v.w,
                        h2.x,h2.y,h2.z,h2.w, h3.x,h3.y,h3.z,h3.w };
    float sqv = 0.f;
#pragma unroll
    for (int o = 0; o < 16; o++) sqv += nodev[o] * nodev[o];
    sq[node] = 0.5f * sqv;
    float xpv[16];
#pragma unroll
    for (int o = 0; o < 16; o++) {
        float a = 0.f;
#pragma unroll
        for (int c = 0; c < 16; c++) a += sWg[o * 16 + c] * nodev[c];
        xpv[o] = a;
        xp[node * 16 + o] = a;
    }
#pragma unroll
    for (int hh = 0; hh < 4; hh++) {
        float as = 0.f, ad = 0.f;
#pragma unroll
        for (int f = 0; f < 4; f++) {
            as += xpv[hh * 4 + f] * sA[hh * 4 + f];
            ad += xpv[hh * 4 + f] * sA[16 + hh * 4 + f];
        }
        asr[node * 4 + hh] = as;
        adt[node * 4 + hh] = ad;
    }
}

// --------- kNN scan: branchless rank-insert, per (row, 512-j slice) top-8 ---
// block = 256 threads = 256 rows scanning the SAME 512-j slice in lock-step
// (wave-uniform j loads, no LDS, no barriers).
// grid = 8 b * 16 rowgroups * 8 slices = 1024 blocks (4 waves/SIMD).
// insert: s'[k] = max(s[k], min(s[k-1], sc)) — 2 fp ops/stage, no branches;
// ids via c[k] = (s[k] >= sc) + 2 cndmask/stage. ">=" keeps earliest j on ties
// (ascending j in slice) == jax top_k tie rule.
__launch_bounds__(256)
__global__ void k_scan(const float* __restrict__ h, const float* __restrict__ sq,
                       uint4* __restrict__ cand_i) {
    int tid = threadIdx.x;
    int blk = blockIdx.x;
    int b  = blk >> 7;
    int rg = (blk >> 3) & 15;
    int sl = blk & 7;
    int i  = rg * 256 + tid;
    long bN = (long)b * NN;
    const float4* ip = (const float4*)&h[(bN + i) * 16];
    float4 r0 = ip[0], r1 = ip[1], r2 = ip[2], r3 = ip[3];
    float ni[16] = { r0.x,r0.y,r0.z,r0.w, r1.x,r1.y,r1.z,r1.w,
                     r2.x,r2.y,r2.z,r2.w, r3.x,r3.y,r3.z,r3.w };
    float s[8]; int id[8];
#pragma unroll
    for (int k = 0; k < 8; k++) { s[k] = -FLT_MAX; id[k] = 65535; }
    int j0 = sl * 512;
    const float* __restrict__ hj  = h + (bN + j0) * 16;
    const float* __restrict__ sqp = sq + bN + j0;
#pragma unroll 4
    for (int q = 0; q < 512; q++) {
        const float4* np = (const float4*)(hj + q * 16);
        float4 a0 = np[0], a1 = np[1], a2 = np[2], a3 = np[3];
        float sc = dot16m(ni, a0, a1, a2, a3, sqp[q]);
        int j = j0 + q;
        if (j == i) sc = -FLT_MAX;          // self excluded; -FLT_MAX never inserts
        bool c[8];
#pragma unroll
        for (int k = 0; k < 8; k++) c[k] = (s[k] >= sc);
        int nid[8];
        nid[0] = c[0] ? id[0] : j;
#pragma unroll
        for (int k = 7; k >= 1; k--)
            nid[k] = c[k - 1] ? (c[k] ? id[k] : j) : id[k - 1];
#pragma unroll
        for (int k = 7; k >= 1; k--) s[k] = fmaxf(s[k], fminf(s[k - 1], sc));
        s[0] = fmaxf(s[0], sc);
#pragma unroll
        for (int k = 0; k < 8; k++) id[k] = nid[k];
    }
    uint4 pk;
    pk.x = (unsigned)id[0] | ((unsigned)id[1] << 16);
    pk.y = (unsigned)id[2] | ((unsigned)id[3] << 16);
    pk.z = (unsigned)id[4] | ((unsigned)id[5] << 16);
    pk.w = (unsigned)id[6] | ((unsigned)id[7] << 16);
    cand_i[(long)(b * NSL + sl) * NN + i] = pk;
}

// --- merge 8 slice-lists (4 slots x 2 slices, rescore bit-identically) ------
// + GAT epilogue -> p.  grid = 8 b * 64 rowgroups = 512 blocks.
__launch_bounds__(256)
__global__ void k_merge(const uint4* __restrict__ cand_i, const float* __restrict__ h,
                        const float* __restrict__ sq, const float* __restrict__ xp,
                        const float* __restrict__ asr, const float* __restrict__ adt,
                        const float* __restrict__ bg, float* __restrict__ p) {
    __shared__ float ms[64 * 3 * 8];
    __shared__ short mi[64 * 3 * 8];
    int tid = threadIdx.x;
    int blk = blockIdx.x;
    int b = blk >> 6, rg = blk & 63;
    int r = tid & 63, slot = tid >> 6;
    int i = rg * 64 + r;
    long bN = (long)b * NN;
    const float4* ip = (const float4*)&h[(bN + i) * 16];
    float4 q0 = ip[0], q1 = ip[1], q2 = ip[2], q3 = ip[3];
    float ni[16] = { q0.x,q0.y,q0.z,q0.w, q1.x,q1.y,q1.z,q1.w,
                     q2.x,q2.y,q2.z,q2.w, q3.x,q3.y,q3.z,q3.w };
    float fS[8]; int fI[8];
#pragma unroll
    for (int k = 0; k < 8; k++) { fS[k] = -FLT_MAX; fI[k] = 65535; }
#pragma unroll
    for (int s2 = 0; s2 < 2; s2++) {
        int sl = slot * 2 + s2;
        uint4 pk = cand_i[(long)(b * NSL + sl) * NN + i];
        unsigned idx8[8] = { pk.x & 0xFFFF, pk.x >> 16, pk.y & 0xFFFF, pk.y >> 16,
                             pk.z & 0xFFFF, pk.z >> 16, pk.w & 0xFFFF, pk.w >> 16 };
#pragma unroll
        for (int k = 0; k < 8; k++) {
            int j = (int)idx8[k];
            const float4* np = (const float4*)&h[(bN + j) * 16];
            float4 a0 = np[0], a1 = np[1], a2 = np[2], a3 = np[3];
            float sc = dot16m(ni, a0, a1, a2, a3, sq[bN + j]);  // bit-identical to scan
            lins8(fS, fI, sc, j);
        }
    }
    if (slot != 0) {
        float* ds = &ms[(r * 3 + slot - 1) * 8];
        short* di = &mi[(r * 3 + slot - 1) * 8];
#pragma unroll
        for (int k = 0; k < 8; k++) { ds[k] = fS[k]; di[k] = (short)fI[k]; }
    }
    __syncthreads();
    if (slot == 0) {
        for (int s = 0; s < 3; s++) {
            const float* ds = &ms[(r * 3 + s) * 8];
            const short* di = &mi[(r * 3 + s) * 8];
#pragma unroll
            for (int k = 0; k < 8; k++) lins8(fS, fI, ds[k], (int)di[k]);
        }
        int nbrs[9];
#pragma unroll
        for (int e = 0; e < 8; e++) nbrs[e] = fI[e];
        nbrs[8] = i;                                   // self-loop
        float adtv[4];
#pragma unroll
        for (int hh = 0; hh < 4; hh++) adtv[hh] = adt[(bN + i) * 4 + hh];
        float mx[4] = { -FLT_MAX, -FLT_MAX, -FLT_MAX, -FLT_MAX };
        float lg[9][4];
#pragma unroll
        for (int e = 0; e < 9; e++) {
            long nb = bN + nbrs[e];
#pragma unroll
            for (int hh = 0; hh < 4; hh++) {
                float l = asr[nb * 4 + hh] + adtv[hh];
                l = (l > 0.f) ? l : 0.2f * l;          // leaky_relu 0.2
                lg[e][hh] = l;
                mx[hh] = fmaxf(mx[hh], l);
            }
        }
        float sum[4] = { 0, 0, 0, 0 };
        float acc[16];
#pragma unroll
        for (int c = 0; c < 16; c++) acc[c] = 0.f;
#pragma unroll
        for (int e = 0; e < 9; e++) {
            long nb = bN + nbrs[e];
            const float4* xpn = (const float4*)&xp[nb * 16];
            float4 x0 = xpn[0], x1 = xpn[1], x2 = xpn[2], x3 = xpn[3];
            float xv[16] = { x0.x,x0.y,x0.z,x0.w, x1.x,x1.y,x1.z,x1.w,
                             x2.x,x2.y,x2.z,x2.w, x3.x,x3.y,x3.z,x3.w };
            float wv[4];
#pragma unroll
            for (int hh = 0; hh < 4; hh++) {
                float w = expf(lg[e][hh] - mx[hh]);
                sum[hh] += w; wv[hh] = w;
            }
#pragma unroll
            for (int hh = 0; hh < 4; hh++)
#pragma unroll
                for (int f = 0; f < 4; f++)
                    acc[hh * 4 + f] += wv[hh] * xv[hh * 4 + f];
        }
#pragma unroll
        for (int hh = 0; hh < 4; hh++) {
            float inv = 1.f / sum[hh];
#pragma unroll
            for (int f = 0; f < 4; f++) {
                float o = acc[hh * 4 + f] * inv + bg[hh * 4 + f];
                p[(bN + i) * 16 + hh * 4 + f] = fmaxf(o, 0.f);
            }
        }
    }
}

// ------- 1x1 MLP 16->128->16, fire mask, h += mask*u, 1x1->1 + sigmoid ------
// hd loop split across 2 thread-halves (2x parallelism), LDS combine.
#define USTR 20
__launch_bounds__(256)
__global__ void k_update(const float* __restrict__ p, const float* __restrict__ h,
                         const float* __restrict__ fire, const float* __restrict__ Wu1,
                         const float* __restrict__ bu1, const float* __restrict__ Wu2,
                         const float* __restrict__ bu2, const float* __restrict__ Wo,
                         const float* __restrict__ bo, float* __restrict__ out_low) {
    __shared__ float sU1[128 * 16];
    __shared__ float sU2t[128 * 16];      // [hd][c] = Wu2[c][hd]
    __shared__ float sb1[128];
    __shared__ float uhalf[128 * USTR];
    int tid = threadIdx.x;
    for (int k = tid; k < 2048; k += 256) {
        sU1[k] = Wu1[k];
        sU2t[(k & 127) * 16 + (k >> 7)] = Wu2[k];   // coalesced read, scatter to LDS
    }
    if (tid < 128) sb1[tid] = bu1[tid];
    __syncthreads();
    int lnode = tid & 127, half = tid >> 7;
    long n = (long)blockIdx.x * 128 + lnode;         // 0..32767
    const float4* pp = (const float4*)&p[n * 16];
    float4 p0 = pp[0], p1 = pp[1], p2 = pp[2], p3 = pp[3];
    float pv[16] = { p0.x,p0.y,p0.z,p0.w, p1.x,p1.y,p1.z,p1.w,
                     p2.x,p2.y,p2.z,p2.w, p3.x,p3.y,p3.z,p3.w };
    float u[16];
#pragma unroll
    for (int c = 0; c < 16; c++) u[c] = 0.f;
    int hd0 = half * 64;
    for (int hd = hd0; hd < hd0 + 64; hd++) {
        const float4* r = (const float4*)&sU1[hd * 16];
        float4 r0 = r[0], r1 = r[1], r2 = r[2], r3 = r[3];
        float a = sb1[hd]
            + r0.x*pv[0] + r0.y*pv[1] + r0.z*pv[2] + r0.w*pv[3]
            + r1.x*pv[4] + r1.y*pv[5] + r1.z*pv[6] + r1.w*pv[7]
            + r2.x*pv[8] + r2.y*pv[9] + r2.z*pv[10]+ r2.w*pv[11]
            + r3.x*pv[12]+ r3.y*pv[13]+ r3.z*pv[14]+ r3.w*pv[15];
        a = fmaxf(a, 0.f);
        const float4* tt = (const float4*)&sU2t[hd * 16];
        float4 t0 = tt[0], t1 = tt[1], t2 = tt[2], t3 = tt[3];
        u[0] += t0.x*a; u[1] += t0.y*a; u[2] += t0.z*a; u[3] += t0.w*a;
        u[4] += t1.x*a; u[5] += t1.y*a; u[6] += t1.z*a; u[7] += t1.w*a;
        u[8] += t2.x*a; u[9] += t2.y*a; u[10]+= t2.z*a; u[11]+= t2.w*a;
        u[12]+= t3.x*a; u[13]+= t3.y*a; u[14]+= t3.z*a; u[15]+= t3.w*a;
    }
    if (half == 1) {
        float4* dst = (float4*)&uhalf[lnode * USTR];
        dst[0] = make_float4(u[0], u[1], u[2], u[3]);
        dst[1] = make_float4(u[4], u[5], u[6], u[7]);
        dst[2] = make_float4(u[8], u[9], u[10], u[11]);
        dst[3] = make_float4(u[12], u[13], u[14], u[15]);
    }
    __syncthreads();
    if (half == 0) {
        const float4* src = (const float4*)&uhalf[lnode * USTR];
        float4 o0 = src[0], o1 = src[1], o2 = src[2], o3 = src[3];
        float ou[16] = { o0.x,o0.y,o0.z,o0.w, o1.x,o1.y,o1.z,o1.w,
                         o2.x,o2.y,o2.z,o2.w, o3.x,o3.y,o3.z,o3.w };
        float mask = (fire[n] < 0.5f) ? 1.f : 0.f;
        const float4* hp = (const float4*)&h[n * 16];
        float4 h0 = hp[0], h1v = hp[1], h2 = hp[2], h3 = hp[3];
        float hv[16] = { h0.x,h0.y,h0.z,h0.w, h1v.x,h1v.y,h1v.z,h1v.w,
                         h2.x,h2.y,h2.z,h2.w, h3.x,h3.y,h3.z,h3.w };
        float o = bo[0];
#pragma unroll
        for (int c = 0; c < 16; c++)
            o += Wo[c] * (hv[c] + mask * (u[c] + ou[c] + bu2[c]));
        out_low[n] = 1.f / (1.f + expf(-o));
    }
}

// ---------------- bilinear upsample 64 -> 256 (half-pixel, clamp) -----------
__global__ void k_up(const float* __restrict__ ol, float* __restrict__ out) {
    int t = blockIdx.x * 256 + threadIdx.x;
    if (t >= BATCH * HIGH * HIGH) return;
    int b = t >> 16, oy = (t >> 8) & 255, ox = t & 255;
    float cy = (oy + 0.5f) * 0.25f - 0.5f;
    float cx = (ox + 0.5f) * 0.25f - 0.5f;
    int iy0 = (int)floorf(cy); float fy = cy - (float)iy0;
    int ix0 = (int)floorf(cx); float fx = cx - (float)ix0;
    int y0 = min(max(iy0, 0), 63), y1 = min(max(iy0 + 1, 0), 63);
    int x0 = min(max(ix0, 0), 63), x1 = min(max(ix0 + 1, 0), 63);
    const float* s = ol + b * NN;
    float v = (1.f - fy) * ((1.f - fx) * s[y0 * 64 + x0] + fx * s[y0 * 64 + x1])
            + fy * ((1.f - fx) * s[y1 * 64 + x0] + fx * s[y1 * 64 + x1]);
    out[t] = v;
}

extern "C" void kernel_launch(void* const* d_in, const int* in_sizes, int n_in,
                              void* d_out, int out_size, void* d_ws, size_t ws_size,
                              hipStream_t stream) {
    const float* x    = (const float*)d_in[0];
    const float* fire = (const float*)d_in[1];
    const float* W1   = (const float*)d_in[2];
    const float* b1   = (const float*)d_in[3];
    const float* g1   = (const float*)d_in[4];
    const float* be1  = (const float*)d_in[5];
    const float* m1   = (const float*)d_in[6];
    const float* v1   = (const float*)d_in[7];
    const float* W2   = (const float*)d_in[8];
    const float* b2   = (const float*)d_in[9];
    const float* g2   = (const float*)d_in[10];
    const float* be2  = (const float*)d_in[11];
    const float* m2   = (const float*)d_in[12];
    const float* v2   = (const float*)d_in[13];
    const float* Wg   = (const float*)d_in[14];
    const float* a_src= (const float*)d_in[15];
    const float* a_dst= (const float*)d_in[16];
    const float* bg   = (const float*)d_in[17];
    const float* Wu1  = (const float*)d_in[18];
    const float* bu1  = (const float*)d_in[19];
    const float* Wu2  = (const float*)d_in[20];
    const float* bu2  = (const float*)d_in[21];
    const float* Wo   = (const float*)d_in[22];
    const float* bo   = (const float*)d_in[23];

    float* ws  = (float*)d_ws;
    float* xl  = ws + OFF_XL;
    float* h1  = ws + OFF_H1;
    float* h   = ws + OFF_H;
    float* sq  = ws + OFF_SQ;
    float* xp  = ws + OFF_XP;
    float* asr = ws + OFF_ASR;
    float* adt = ws + OFF_ADT;
    float* p   = ws + OFF_P;
    float* ol  = ws + OFF_OL;
    uint4* cand_i = (uint4*)(ws + OFF_H1);          // reuse h1 (dead after conv2o), 4 MB

    k_down  <<<(BATCH * NN + 127) / 128, 128, 0, stream>>>(x, xl);
    k_conv1 <<<(BATCH * C1 * NN) / 256, 256, 0, stream>>>(xl, W1, b1, g1, be1, m1, v1, h1);
    k_conv2o<<<BATCH * 32 * 2, 128, 0, stream>>>(h1, W2, b2, g2, be2, m2, v2, h);
    k_feats <<<BATCH * NN / 128, 128, 0, stream>>>(h, Wg, a_src, a_dst, sq, xp, asr, adt);
    k_scan  <<<BATCH * 16 * NSL, 256, 0, stream>>>(h, sq, cand_i);
    k_merge <<<BATCH * 64, 256, 0, stream>>>(cand_i, h, sq, xp, asr, adt, bg, p);
    k_update<<<BATCH * NN / 128, 256, 0, stream>>>(p, h, fire, Wu1, bu1, Wu2, bu2, Wo, bo, ol);
    k_up    <<<(BATCH * HIGH * HIGH) / 256, 256, 0, stream>>>(ol, (float*)d_out);
}

// Round 9
// 437.714 us; speedup vs baseline: 1.0934x; 1.0150x over previous
//
#include <hip/hip_runtime.h>
#include <math.h>
#include <float.h>

#define BATCH 8
#define HIGH  256
#define LOWR  64
#define NN    4096          // LOWR*LOWR
#define HIDC  16
#define C1    64
#define NSL   8             // j-slices in kNN scan (512 j each)

// workspace layout (floats) — footprint identical to the validated R1/R2 layout
#define OFF_XL   0
#define OFF_H1   (OFF_XL  + BATCH*NN)            // 2,097,152 floats; reused for cand_i
#define OFF_H    (OFF_H1  + BATCH*C1*NN)         // node-major [B*N][16]
#define OFF_SQ   (OFF_H   + BATCH*NN*HIDC)       // 0.5*|h|^2 per node
#define OFF_XP   (OFF_SQ  + BATCH*NN)
#define OFF_ASR  (OFF_XP  + BATCH*NN*HIDC)
#define OFF_ADT  (OFF_ASR + BATCH*NN*4)
#define OFF_P    (OFF_ADT + BATCH*NN*4)         // (slot kept; p no longer materialized)
#define OFF_OL   (OFF_P   + BATCH*NN*HIDC)
// cand_i: BATCH*NSL*NN uint4 = 4 MB = 1,048,576 float-slots at OFF_H1 (validated in R5)

// identical-arithmetic dot used by BOTH k_scan and k_merge (bit-equal scores)
__device__ __forceinline__ float dot16m(const float ni[16], float4 a0, float4 a1,
                                        float4 a2, float4 a3, float hs) {
    return ni[0]*a0.x + ni[1]*a0.y + ni[2]*a0.z + ni[3]*a0.w
         + ni[4]*a1.x + ni[5]*a1.y + ni[6]*a1.z + ni[7]*a1.w
         + ni[8]*a2.x + ni[9]*a2.y + ni[10]*a2.z + ni[11]*a2.w
         + ni[12]*a3.x + ni[13]*a3.y + ni[14]*a3.z + ni[15]*a3.w
         - hs;
}

// lex (score desc, idx asc) insert for the merge (matches jax top_k tie rule)
__device__ __forceinline__ void lins8(float s[8], int id[8], float sc, int j) {
    if ((sc > s[7]) || (sc == s[7] && j < id[7])) {
        s[7] = sc; id[7] = j;
#pragma unroll
        for (int k = 7; k > 0; k--) {
            if ((s[k] > s[k - 1]) || (s[k] == s[k - 1] && id[k] < id[k - 1])) {
                float td = s[k]; s[k] = s[k - 1]; s[k - 1] = td;
                int tj = id[k]; id[k] = id[k - 1]; id[k - 1] = tj;
            }
        }
    }
}

// ---------------- bilinear downsample 256 -> 64 (antialiased triangle) -------
__global__ void k_down(const float* __restrict__ x, float* __restrict__ xl) {
    int t = blockIdx.x * 128 + threadIdx.x;
    if (t >= BATCH * NN) return;
    int b = t >> 12, oy = (t >> 6) & 63, ox = t & 63;
    const float* xb = x + b * HIGH * HIGH;
    float cy = 4.f * oy + 1.5f, cx = 4.f * ox + 1.5f;
    float wy[8], wx[8], sy = 0.f, sx = 0.f;
#pragma unroll
    for (int k = 0; k < 8; k++) {
        int iy = 4 * oy - 2 + k;
        float w = 1.f - fabsf((float)iy - cy) * 0.25f;
        if (iy < 0 || iy >= HIGH) w = 0.f;
        wy[k] = w; sy += w;
        int ix = 4 * ox - 2 + k;
        float v = 1.f - fabsf((float)ix - cx) * 0.25f;
        if (ix < 0 || ix >= HIGH) v = 0.f;
        wx[k] = v; sx += v;
    }
    float acc = 0.f;
#pragma unroll
    for (int ky = 0; ky < 8; ky++) {
        if (wy[ky] == 0.f) continue;
        int iy = 4 * oy - 2 + ky;
        float rowacc = 0.f;
#pragma unroll
        for (int kx = 0; kx < 8; kx++) {
            if (wx[kx] == 0.f) continue;
            int ix = 4 * ox - 2 + kx;
            rowacc += wx[kx] * xb[iy * HIGH + ix];
        }
        acc += wy[ky] * rowacc;
    }
    xl[t] = acc / (sy * sx);
}

// ---------------- conv3x3 1->64 + BN + relu ---------------------------------
__global__ void k_conv1(const float* __restrict__ xl, const float* __restrict__ W1,
                        const float* __restrict__ b1, const float* __restrict__ g1,
                        const float* __restrict__ be1, const float* __restrict__ m1,
                        const float* __restrict__ v1, float* __restrict__ h1) {
    int t = blockIdx.x * 256 + threadIdx.x;
    if (t >= BATCH * C1 * NN) return;
    int b = t >> 18, co = (t >> 12) & 63, y = (t >> 6) & 63, x = t & 63;
    const float* src = xl + b * NN;
    const float* w = W1 + co * 9;
    float acc = 0.f;
#pragma unroll
    for (int dy = -1; dy <= 1; dy++) {
        int yy = y + dy; if (yy < 0 || yy >= 64) continue;
#pragma unroll
        for (int dx = -1; dx <= 1; dx++) {
            int xx = x + dx; if (xx < 0 || xx >= 64) continue;
            acc += w[(dy + 1) * 3 + (dx + 1)] * src[yy * 64 + xx];
        }
    }
    acc += b1[co];
    float sc = g1[co] / sqrtf(v1[co] + 1e-5f);
    acc = (acc - m1[co]) * sc + be1[co];
    h1[t] = fmaxf(acc, 0.f);
}

// ------- conv3x3 64->16 + BN + relu, split over 2 output-channel halves ------
__launch_bounds__(128)
__global__ void k_conv2o(const float* __restrict__ h1, const float* __restrict__ W2,
                         const float* __restrict__ b2, const float* __restrict__ g2,
                         const float* __restrict__ be2, const float* __restrict__ m2,
                         const float* __restrict__ v2, float* __restrict__ h) {
    __shared__ float sW[576 * 8];       // [ci*9+tap][o']
    int tid = threadIdx.x;
    int blk = blockIdx.x;
    int b = blk >> 6, ytile = (blk >> 1) & 31, oh = blk & 1;
    for (int k = tid; k < 4608; k += 128) {
        int o = k / 576, ct = k - o * 576;
        sW[ct * 8 + o] = W2[(oh * 8 + o) * 576 + ct];
    }
    __syncthreads();
    int ty = tid >> 6, x = tid & 63, y = ytile * 2 + ty;
    float acc[8];
#pragma unroll
    for (int o = 0; o < 8; o++) acc[o] = 0.f;
    const float* hb = h1 + (long)b * C1 * NN;
    for (int ci = 0; ci < 64; ci++) {
        const float* plane = hb + ci * NN;
#pragma unroll
        for (int dy = -1; dy <= 1; dy++) {
            int yy = y + dy; bool oky = (yy >= 0 && yy < 64);
#pragma unroll
            for (int dx = -1; dx <= 1; dx++) {
                int xx = x + dx;
                float v = (oky && xx >= 0 && xx < 64) ? plane[yy * 64 + xx] : 0.f;
                int ct = ci * 9 + (dy + 1) * 3 + (dx + 1);
                const float4* wr = (const float4*)&sW[ct * 8];
                float4 w0 = wr[0], w1 = wr[1];
                acc[0] += v * w0.x; acc[1] += v * w0.y; acc[2] += v * w0.z; acc[3] += v * w0.w;
                acc[4] += v * w1.x; acc[5] += v * w1.y; acc[6] += v * w1.z; acc[7] += v * w1.w;
            }
        }
    }
    int n = y * 64 + x;
    long node = (long)b * NN + n;
#pragma unroll
    for (int o2 = 0; o2 < 8; o2++) {
        int o = oh * 8 + o2;
        float a = acc[o2] + b2[o];
        float sc = g2[o] / sqrtf(v2[o] + 1e-5f);
        a = (a - m2[o]) * sc + be2[o];
        h[node * 16 + o] = fmaxf(a, 0.f);
    }
}

// ------- per-node derived features: sq (0.5|h|^2), xp = Wg h, asr, adt ------
__launch_bounds__(128)
__global__ void k_feats(const float* __restrict__ h, const float* __restrict__ Wg,
                        const float* __restrict__ a_src, const float* __restrict__ a_dst,
                        float* __restrict__ sq, float* __restrict__ xp,
                        float* __restrict__ asr, float* __restrict__ adt) {
    __shared__ float sWg[256];
    __shared__ float sA[32];
    int tid = threadIdx.x;
    for (int k = tid; k < 256; k += 128) sWg[k] = Wg[k];
    if (tid < 16) { sA[tid] = a_src[tid]; sA[16 + tid] = a_dst[tid]; }
    __syncthreads();
    long node = (long)blockIdx.x * 128 + tid;
    const float4* hp = (const float4*)&h[node * 16];
    float4 h0 = hp[0], h1v = hp[1], h2 = hp[2], h3 = hp[3];
    float nodev[16] = { h0.x,h0.y,h0.z,h0.w, h1v.x,h1v.y,h1v.z,h1v.w,
                        h2.x,h2.y,h2.z,h2.w, h3.x,h3.y,h3.z,h3.w };
    float sqv = 0.f;
#pragma unroll
    for (int o = 0; o < 16; o++) sqv += nodev[o] * nodev[o];
    sq[node] = 0.5f * sqv;
    float xpv[16];
#pragma unroll
    for (int o = 0; o < 16; o++) {
        float a = 0.f;
#pragma unroll
        for (int c = 0; c < 16; c++) a += sWg[o * 16 + c] * nodev[c];
        xpv[o] = a;
        xp[node * 16 + o] = a;
    }
#pragma unroll
    for (int hh = 0; hh < 4; hh++) {
        float as = 0.f, ad = 0.f;
#pragma unroll
        for (int f = 0; f < 4; f++) {
            as += xpv[hh * 4 + f] * sA[hh * 4 + f];
            ad += xpv[hh * 4 + f] * sA[16 + hh * 4 + f];
        }
        asr[node * 4 + hh] = as;
        adt[node * 4 + hh] = ad;
    }
}

// --------- kNN scan: guarded branchless rank-insert, per (row, slice) top-8 -
// block = 256 threads = 256 rows scanning the SAME 512-j slice in lock-step
// (wave-uniform j loads -> scalar broadcast, no LDS, no barriers).
// grid = 8 b * 16 rowgroups * 8 slices = 1024 blocks (4 waves/SIMD).
// guard skips iters where no lane inserts-ish; body is the branchless
// max/min rank-insert (no swap chains). ">=" placement + strict guard
// keeps earliest j on ties == jax top_k tie rule.
__launch_bounds__(256)
__global__ void k_scan(const float* __restrict__ h, const float* __restrict__ sq,
                       uint4* __restrict__ cand_i) {
    int tid = threadIdx.x;
    int blk = blockIdx.x;
    int b  = blk >> 7;
    int rg = (blk >> 3) & 15;
    int sl = blk & 7;
    int i  = rg * 256 + tid;
    long bN = (long)b * NN;
    const float4* ip = (const float4*)&h[(bN + i) * 16];
    float4 r0 = ip[0], r1 = ip[1], r2 = ip[2], r3 = ip[3];
    float ni[16] = { r0.x,r0.y,r0.z,r0.w, r1.x,r1.y,r1.z,r1.w,
                     r2.x,r2.y,r2.z,r2.w, r3.x,r3.y,r3.z,r3.w };
    float s[8]; int id[8];
#pragma unroll
    for (int k = 0; k < 8; k++) { s[k] = -FLT_MAX; id[k] = 65535; }
    int j0 = sl * 512;
    const float* __restrict__ hj  = h + (bN + j0) * 16;
    const float* __restrict__ sqp = sq + bN + j0;
#pragma unroll 4
    for (int q = 0; q < 512; q++) {
        const float4* np = (const float4*)(hj + q * 16);
        float4 a0 = np[0], a1 = np[1], a2 = np[2], a3 = np[3];
        float sc = dot16m(ni, a0, a1, a2, a3, sqp[q]);
        int j = j0 + q;
        if (j == i) sc = -FLT_MAX;          // self excluded; never passes strict guard
        if (sc > s[7]) {
            bool c[7];
#pragma unroll
            for (int k = 0; k < 7; k++) c[k] = (s[k] >= sc);
            int nid[8];
            nid[0] = c[0] ? id[0] : j;
#pragma unroll
            for (int k = 1; k < 7; k++)
                nid[k] = c[k - 1] ? (c[k] ? id[k] : j) : id[k - 1];
            nid[7] = c[6] ? j : id[6];
            s[7] = fminf(s[6], sc);
#pragma unroll
            for (int k = 6; k >= 1; k--) s[k] = fmaxf(s[k], fminf(s[k - 1], sc));
            s[0] = fmaxf(s[0], sc);
#pragma unroll
            for (int k = 0; k < 8; k++) id[k] = nid[k];
        }
    }
    uint4 pk;
    pk.x = (unsigned)id[0] | ((unsigned)id[1] << 16);
    pk.y = (unsigned)id[2] | ((unsigned)id[3] << 16);
    pk.z = (unsigned)id[4] | ((unsigned)id[5] << 16);
    pk.w = (unsigned)id[6] | ((unsigned)id[7] << 16);
    cand_i[(long)(b * NSL + sl) * NN + i] = pk;
}

// --- merge 8 slice-lists (4 slots x 2 slices, rescore bit-identically) ------
// + GAT epilogue + FUSED update-MLP + fire mask + 1x1 out + sigmoid -> ol.
// grid = 8 b * 64 rowgroups = 512 blocks.  p never materialized.
__launch_bounds__(256)
__global__ void k_merge(const uint4* __restrict__ cand_i, const float* __restrict__ h,
                        const float* __restrict__ sq, const float* __restrict__ xp,
                        const float* __restrict__ asr, const float* __restrict__ adt,
                        const float* __restrict__ bg, const float* __restrict__ fire,
                        const float* __restrict__ Wu1, const float* __restrict__ bu1,
                        const float* __restrict__ Wu2, const float* __restrict__ bu2,
                        const float* __restrict__ Wo, const float* __restrict__ bo,
                        float* __restrict__ out_low) {
    __shared__ float ms[64 * 3 * 8];
    __shared__ short mi[64 * 3 * 8];
    __shared__ float sU1[128 * 16];       // Wu1 [hd][c]
    __shared__ float sU2t[128 * 16];      // [hd][c] = Wu2[c][hd]
    __shared__ float sb1[128];
    int tid = threadIdx.x;
    for (int k = tid; k < 2048; k += 256) {
        sU1[k] = Wu1[k];
        sU2t[(k & 127) * 16 + (k >> 7)] = Wu2[k];
    }
    if (tid < 128) sb1[tid] = bu1[tid];
    int blk = blockIdx.x;
    int b = blk >> 6, rg = blk & 63;
    int r = tid & 63, slot = tid >> 6;
    int i = rg * 64 + r;
    long bN = (long)b * NN;
    const float4* ip = (const float4*)&h[(bN + i) * 16];
    float4 q0 = ip[0], q1 = ip[1], q2 = ip[2], q3 = ip[3];
    float ni[16] = { q0.x,q0.y,q0.z,q0.w, q1.x,q1.y,q1.z,q1.w,
                     q2.x,q2.y,q2.z,q2.w, q3.x,q3.y,q3.z,q3.w };
    float fS[8]; int fI[8];
#pragma unroll
    for (int k = 0; k < 8; k++) { fS[k] = -FLT_MAX; fI[k] = 65535; }
#pragma unroll
    for (int s2 = 0; s2 < 2; s2++) {
        int sl = slot * 2 + s2;
        uint4 pk = cand_i[(long)(b * NSL + sl) * NN + i];
        unsigned idx8[8] = { pk.x & 0xFFFF, pk.x >> 16, pk.y & 0xFFFF, pk.y >> 16,
                             pk.z & 0xFFFF, pk.z >> 16, pk.w & 0xFFFF, pk.w >> 16 };
#pragma unroll
        for (int k = 0; k < 8; k++) {
            int j = (int)idx8[k];
            const float4* np = (const float4*)&h[(bN + j) * 16];
            float4 a0 = np[0], a1 = np[1], a2 = np[2], a3 = np[3];
            float sc = dot16m(ni, a0, a1, a2, a3, sq[bN + j]);  // bit-identical to scan
            lins8(fS, fI, sc, j);
        }
    }
    if (slot != 0) {
        float* ds = &ms[(r * 3 + slot - 1) * 8];
        short* di = &mi[(r * 3 + slot - 1) * 8];
#pragma unroll
        for (int k = 0; k < 8; k++) { ds[k] = fS[k]; di[k] = (short)fI[k]; }
    }
    __syncthreads();
    if (slot == 0) {
        for (int s = 0; s < 3; s++) {
            const float* ds = &ms[(r * 3 + s) * 8];
            const short* di = &mi[(r * 3 + s) * 8];
#pragma unroll
            for (int k = 0; k < 8; k++) lins8(fS, fI, ds[k], (int)di[k]);
        }
        int nbrs[9];
#pragma unroll
        for (int e = 0; e < 8; e++) nbrs[e] = fI[e];
        nbrs[8] = i;                                   // self-loop
        float adtv[4];
#pragma unroll
        for (int hh = 0; hh < 4; hh++) adtv[hh] = adt[(bN + i) * 4 + hh];
        float mx[4] = { -FLT_MAX, -FLT_MAX, -FLT_MAX, -FLT_MAX };
        float lg[9][4];
#pragma unroll
        for (int e = 0; e < 9; e++) {
            long nb = bN + nbrs[e];
#pragma unroll
            for (int hh = 0; hh < 4; hh++) {
                float l = asr[nb * 4 + hh] + adtv[hh];
                l = (l > 0.f) ? l : 0.2f * l;          // leaky_relu 0.2
                lg[e][hh] = l;
                mx[hh] = fmaxf(mx[hh], l);
            }
        }
        float sum[4] = { 0, 0, 0, 0 };
        float acc[16];
#pragma unroll
        for (int c = 0; c < 16; c++) acc[c] = 0.f;
#pragma unroll
        for (int e = 0; e < 9; e++) {
            long nb = bN + nbrs[e];
            const float4* xpn = (const float4*)&xp[nb * 16];
            float4 x0 = xpn[0], x1 = xpn[1], x2 = xpn[2], x3 = xpn[3];
            float xv[16] = { x0.x,x0.y,x0.z,x0.w, x1.x,x1.y,x1.z,x1.w,
                             x2.x,x2.y,x2.z,x2.w, x3.x,x3.y,x3.z,x3.w };
            float wv[4];
#pragma unroll
            for (int hh = 0; hh < 4; hh++) {
                float w = expf(lg[e][hh] - mx[hh]);
                sum[hh] += w; wv[hh] = w;
            }
#pragma unroll
            for (int hh = 0; hh < 4; hh++)
#pragma unroll
                for (int f = 0; f < 4; f++)
                    acc[hh * 4 + f] += wv[hh] * xv[hh * 4 + f];
        }
        float pv[16];
#pragma unroll
        for (int hh = 0; hh < 4; hh++) {
            float inv = 1.f / sum[hh];
#pragma unroll
            for (int f = 0; f < 4; f++) {
                float o = acc[hh * 4 + f] * inv + bg[hh * 4 + f];
                pv[hh * 4 + f] = fmaxf(o, 0.f);        // p (GrapherModule relu)
            }
        }
        // ---- fused update net: u = Wu2 relu(Wu1 p + bu1) + bu2 ----
        float u[16];
#pragma unroll
        for (int c = 0; c < 16; c++) u[c] = bu2[c];
        for (int hd = 0; hd < 128; hd++) {
            const float4* rw = (const float4*)&sU1[hd * 16];
            float4 w0 = rw[0], w1 = rw[1], w2 = rw[2], w3 = rw[3];
            float a = sb1[hd]
                + w0.x*pv[0] + w0.y*pv[1] + w0.z*pv[2] + w0.w*pv[3]
                + w1.x*pv[4] + w1.y*pv[5] + w1.z*pv[6] + w1.w*pv[7]
                + w2.x*pv[8] + w2.y*pv[9] + w2.z*pv[10]+ w2.w*pv[11]
                + w3.x*pv[12]+ w3.y*pv[13]+ w3.z*pv[14]+ w3.w*pv[15];
            a = fmaxf(a, 0.f);
            const float4* tt = (const float4*)&sU2t[hd * 16];
            float4 t0 = tt[0], t1 = tt[1], t2 = tt[2], t3 = tt[3];
            u[0] += t0.x*a; u[1] += t0.y*a; u[2] += t0.z*a; u[3] += t0.w*a;
            u[4] += t1.x*a; u[5] += t1.y*a; u[6] += t1.z*a; u[7] += t1.w*a;
            u[8] += t2.x*a; u[9] += t2.y*a; u[10]+= t2.z*a; u[11]+= t2.w*a;
            u[12]+= t3.x*a; u[13]+= t3.y*a; u[14]+= t3.z*a; u[15]+= t3.w*a;
        }
        float mask = (fire[bN + i] < 0.5f) ? 1.f : 0.f;
        float o = bo[0];
#pragma unroll
        for (int c = 0; c < 16; c++) o += Wo[c] * (ni[c] + mask * u[c]);  // ni == h[node]
        out_low[bN + i] = 1.f / (1.f + expf(-o));
    }
}

// ---------------- bilinear upsample 64 -> 256 (half-pixel, clamp) -----------
__global__ void k_up(const float* __restrict__ ol, float* __restrict__ out) {
    int t = blockIdx.x * 256 + threadIdx.x;
    if (t >= BATCH * HIGH * HIGH) return;
    int b = t >> 16, oy = (t >> 8) & 255, ox = t & 255;
    float cy = (oy + 0.5f) * 0.25f - 0.5f;
    float cx = (ox + 0.5f) * 0.25f - 0.5f;
    int iy0 = (int)floorf(cy); float fy = cy - (float)iy0;
    int ix0 = (int)floorf(cx); float fx = cx - (float)ix0;
    int y0 = min(max(iy0, 0), 63), y1 = min(max(iy0 + 1, 0), 63);
    int x0 = min(max(ix0, 0), 63), x1 = min(max(ix0 + 1, 0), 63);
    const float* s = ol + b * NN;
    float v = (1.f - fy) * ((1.f - fx) * s[y0 * 64 + x0] + fx * s[y0 * 64 + x1])
            + fy * ((1.f - fx) * s[y1 * 64 + x0] + fx * s[y1 * 64 + x1]);
    out[t] = v;
}

extern "C" void kernel_launch(void* const* d_in, const int* in_sizes, int n_in,
                              void* d_out, int out_size, void* d_ws, size_t ws_size,
                              hipStream_t stream) {
    const float* x    = (const float*)d_in[0];
    const float* fire = (const float*)d_in[1];
    const float* W1   = (const float*)d_in[2];
    const float* b1   = (const float*)d_in[3];
    const float* g1   = (const float*)d_in[4];
    const float* be1  = (const float*)d_in[5];
    const float* m1   = (const float*)d_in[6];
    const float* v1   = (const float*)d_in[7];
    const float* W2   = (const float*)d_in[8];
    const float* b2   = (const float*)d_in[9];
    const float* g2   = (const float*)d_in[10];
    const float* be2  = (const float*)d_in[11];
    const float* m2   = (const float*)d_in[12];
    const float* v2   = (const float*)d_in[13];
    const float* Wg   = (const float*)d_in[14];
    const float* a_src= (const float*)d_in[15];
    const float* a_dst= (const float*)d_in[16];
    const float* bg   = (const float*)d_in[17];
    const float* Wu1  = (const float*)d_in[18];
    const float* bu1  = (const float*)d_in[19];
    const float* Wu2  = (const float*)d_in[20];
    const float* bu2  = (const float*)d_in[21];
    const float* Wo   = (const float*)d_in[22];
    const float* bo   = (const float*)d_in[23];

    float* ws  = (float*)d_ws;
    float* xl  = ws + OFF_XL;
    float* h1  = ws + OFF_H1;
    float* h   = ws + OFF_H;
    float* sq  = ws + OFF_SQ;
    float* xp  = ws + OFF_XP;
    float* asr = ws + OFF_ASR;
    float* adt = ws + OFF_ADT;
    float* ol  = ws + OFF_OL;
    uint4* cand_i = (uint4*)(ws + OFF_H1);          // reuse h1 (dead after conv2o), 4 MB

    k_down  <<<(BATCH * NN + 127) / 128, 128, 0, stream>>>(x, xl);
    k_conv1 <<<(BATCH * C1 * NN) / 256, 256, 0, stream>>>(xl, W1, b1, g1, be1, m1, v1, h1);
    k_conv2o<<<BATCH * 32 * 2, 128, 0, stream>>>(h1, W2, b2, g2, be2, m2, v2, h);
    k_feats <<<BATCH * NN / 128, 128, 0, stream>>>(h, Wg, a_src, a_dst, sq, xp, asr, adt);
    k_scan  <<<BATCH * 16 * NSL, 256, 0, stream>>>(h, sq, cand_i);
    k_merge <<<BATCH * 64, 256, 0, stream>>>(cand_i, h, sq, xp, asr, adt, bg, fire,
                                             Wu1, bu1, Wu2, bu2, Wo, bo, ol);
    k_up    <<<(BATCH * HIGH * HIGH) / 256, 256, 0, stream>>>(ol, (float*)d_out);
}